// Round 1
// baseline (449.320 us; speedup 1.0000x reference)
//
#include <hip/hip_runtime.h>

// QuadraticBaseMorpho: out[h][w] = max_{dy,dx in [-3,3]} xpad[h+dy][w+dx] + nb[dy+3][dx+3]
// xpad is x padded with -10000; nb is a quadratic SE (normalized, negated),
// center forced to -10000 (excluded). Input (8,64,256,256) fp32 = 512 planes of 256x256.

#define MAXV 10000.0f

constexpr int H = 256;
constexpr int W = 256;
constexpr int TILE_ROWS = 32;
constexpr int LDS_ROWS = TILE_ROWS + 6;   // 38
constexpr int LDS_STRIDE = 264;           // 262 cols used, padded for 16B-aligned rows
constexpr int ROW_TILES = H / TILE_ROWS;  // 8

__global__ __launch_bounds__(256) void morpho_kernel(
    const float* __restrict__ x,
    const float* __restrict__ k1p,
    const float* __restrict__ k2p,
    const float* __restrict__ k3p,
    float* __restrict__ out) {
  __shared__ __align__(16) float tile[LDS_ROWS * LDS_STRIDE];
  __shared__ float s_se[49];
  __shared__ float s_nb[49];

  const int tid = threadIdx.x;
  const int p = blockIdx.x >> 3;                 // plane index (512 planes)
  const int ty0 = (blockIdx.x & 7) * TILE_ROWS;  // tile's first output row

  const float* __restrict__ xp = x + (size_t)p * (H * W);
  float* __restrict__ op = out + (size_t)p * (H * W);

  // ---- structuring element, stage 1: raw quadratic form (49 threads) ----
  if (tid < 49) {
    const float k1v = k1p[0], k2v = k2p[0], k3v = k3p[0];
    const int a = tid / 7, b = tid % 7;          // a: y index, b: x index ('xy' meshgrid)
    const float xg = (float)(b - 3);
    const float yg = (float)(a - 3);
    // matches jnp eval order: k1*xg^2 + 2.0*k2*xg*yg + k3*yg^2
    s_se[tid] = k1v * (xg * xg) + 2.0f * k2v * xg * yg + k3v * (yg * yg);
  }

  // ---- stage the input tile (rows ty0-3 .. ty0+34, cols -3 .. 258) ----
  for (int r = 0; r < LDS_ROWS; ++r) {
    const int gy = ty0 - 3 + r;
    const bool rowok = (unsigned)gy < (unsigned)H;
    {
      const int gx = tid - 3;                    // LDS col = tid
      float v = -MAXV;
      if (rowok && (unsigned)gx < (unsigned)W) v = xp[gy * W + gx];
      tile[r * LDS_STRIDE + tid] = v;
    }
    if (tid < 6) {                               // tail cols 256..261 (gx 253..258)
      const int c = 256 + tid;
      const int gx = c - 3;
      float v = -MAXV;
      if (rowok && (unsigned)gx < (unsigned)W) v = xp[gy * W + gx];
      tile[r * LDS_STRIDE + c] = v;
    }
  }
  __syncthreads();

  // ---- structuring element, stage 2: normalize, negate, flip, mask center ----
  if (tid < 49) {
    float m = s_se[0];
#pragma unroll
    for (int i = 1; i < 49; ++i) m = fmaxf(m, s_se[i]);
    const int i = tid / 7, j = tid % 7;
    const int a = 6 - i, b = 6 - j;              // nb = neighborhood[::-1, ::-1]
    s_nb[tid] = (a == 3 && b == 3) ? -MAXV : -(s_se[a * 7 + b] / m);
  }
  __syncthreads();

  // hoist SE weights into registers (uniform broadcast reads)
  float nbr[49];
#pragma unroll
  for (int i = 0; i < 49; ++i) nbr[i] = s_nb[i];

  // ---- compute: each thread owns an 8-col x 4-row output patch ----
  const int tx = tid & 31;                       // 32 threads across -> 8 cols each
  const int tyq = tid >> 5;                      // 8 threads down   -> 4 rows each
  const int o0 = tx * 8;                         // output col base (global == tile col)
  const int r0 = tyq * 4;                        // output row base within tile

  float acc[4][8];
#pragma unroll
  for (int t = 0; t < 4; ++t)
#pragma unroll
    for (int c = 0; c < 8; ++c) acc[t][c] = -INFINITY;

#pragma unroll
  for (int iy = 0; iy < 10; ++iy) {              // input rows r0-3 .. r0+6 (LDS rows r0+iy)
    float buf[16];
    const float* rp = &tile[(r0 + iy) * LDS_STRIDE + o0];
#pragma unroll
    for (int q = 0; q < 4; ++q) {                // 4x ds_read_b128, 16B aligned
      const float4 v = *reinterpret_cast<const float4*>(rp + 4 * q);
      buf[4 * q + 0] = v.x;
      buf[4 * q + 1] = v.y;
      buf[4 * q + 2] = v.z;
      buf[4 * q + 3] = v.w;
    }
#pragma unroll
    for (int t = 0; t < 4; ++t) {
      const int dyr = iy - t;                    // nb row index = dy+3
      if (dyr < 0 || dyr > 6) continue;          // dead code after unroll
#pragma unroll
      for (int c = 0; c < 8; ++c) {
        // 7 adds + max tree (folds to v_max3_f32)
        const float s0 = buf[c + 0] + nbr[dyr * 7 + 0];
        const float s1 = buf[c + 1] + nbr[dyr * 7 + 1];
        const float s2 = buf[c + 2] + nbr[dyr * 7 + 2];
        const float s3 = buf[c + 3] + nbr[dyr * 7 + 3];
        const float s4 = buf[c + 4] + nbr[dyr * 7 + 4];
        const float s5 = buf[c + 5] + nbr[dyr * 7 + 5];
        const float s6 = buf[c + 6] + nbr[dyr * 7 + 6];
        const float m0 = fmaxf(fmaxf(s0, s1), s2);
        const float m1 = fmaxf(fmaxf(s3, s4), s5);
        acc[t][c] = fmaxf(fmaxf(acc[t][c], s6), fmaxf(m0, m1));
      }
    }
  }

  // ---- store: 2x float4 per output row ----
#pragma unroll
  for (int t = 0; t < 4; ++t) {
    const int gy = ty0 + r0 + t;
    float4 v0, v1;
    v0.x = acc[t][0]; v0.y = acc[t][1]; v0.z = acc[t][2]; v0.w = acc[t][3];
    v1.x = acc[t][4]; v1.y = acc[t][5]; v1.z = acc[t][6]; v1.w = acc[t][7];
    *reinterpret_cast<float4*>(&op[gy * W + o0]) = v0;
    *reinterpret_cast<float4*>(&op[gy * W + o0 + 4]) = v1;
  }
}

extern "C" void kernel_launch(void* const* d_in, const int* in_sizes, int n_in,
                              void* d_out, int out_size, void* d_ws, size_t ws_size,
                              hipStream_t stream) {
  const float* x = (const float*)d_in[0];
  const float* k1 = (const float*)d_in[1];
  const float* k2 = (const float*)d_in[2];
  const float* k3 = (const float*)d_in[3];
  float* out = (float*)d_out;

  const int planes = 8 * 64;                       // 512
  const int blocks = planes * ROW_TILES;           // 4096
  morpho_kernel<<<dim3(blocks), dim3(256), 0, stream>>>(x, k1, k2, k3, out);
}

// Round 2
// 287.065 us; speedup vs baseline: 1.5652x; 1.5652x over previous
//
#include <hip/hip_runtime.h>

// QuadraticBaseMorpho: out[h][w] = max_{dy,dx in [-3,3]} xpad[h+dy][w+dx] + nb[dy+3][dx+3]
// xpad = x padded with -10000. nb = -(se/se.max()) with center forced to -10000.
// se = k1*xg^2 + 2*k2*xg*yg + k3*yg^2 is even-symmetric, so the [::-1,::-1] flip
// is the identity. Input (8,64,256,256) fp32 = 512 planes of 256x256.

#define MAXV 10000.0f

constexpr int H = 256;
constexpr int W = 256;
constexpr int TILE_ROWS = 16;              // output rows per block
constexpr int LDS_ROWS = TILE_ROWS + 6;    // 22
constexpr int LDS_STRIDE = 264;            // cols: 4 left halo + 256 data + 4 right; 1056 B rows (16B-aligned)
constexpr int ROW_TILES = H / TILE_ROWS;   // 16
constexpr int R = 4;                       // output rows per thread (4 wave-row-groups x 4)

__device__ __forceinline__ float rfl(float x) {
  return __int_as_float(__builtin_amdgcn_readfirstlane(__float_as_int(x)));
}

__global__ __launch_bounds__(256, 6) void morpho_kernel(
    const float* __restrict__ x,
    const float* __restrict__ k1p,
    const float* __restrict__ k2p,
    const float* __restrict__ k3p,
    float* __restrict__ out) {
  __shared__ __align__(16) float tile[LDS_ROWS * LDS_STRIDE];

  const int tid = threadIdx.x;
  const int p = blockIdx.x >> 4;                 // plane (512)
  const int ty0 = (blockIdx.x & 15) * TILE_ROWS; // first output row of tile

  const float* __restrict__ xp = x + (size_t)p * (H * W);
  float* __restrict__ op = out + (size_t)p * (H * W);

  // ---- halo fill: cols 0..3 and 260..263 are always out-of-range -> -MAXV ----
  if (tid < LDS_ROWS * 8) {
    const int h = tid & 7;
    const int col = (h < 4) ? h : (256 + h);     // 0..3, 260..263
    const int r = tid >> 3;
    tile[r * LDS_STRIDE + col] = -MAXV;
  }

  // ---- stage interior: float4 per thread, wave-uniform row bounds branch ----
  // 22 rows x 64 float4-chunks; 64 consecutive tids cover exactly one row.
  for (int i = tid; i < LDS_ROWS * 64; i += 256) {
    const int r = i >> 6;
    const int c4 = i & 63;
    const int gy = ty0 - 3 + r;
    float4 v;
    if ((unsigned)gy < (unsigned)H) {            // uniform across the 64-lane wave
      v = *reinterpret_cast<const float4*>(&xp[gy * W + c4 * 4]);
    } else {
      v.x = v.y = v.z = v.w = -MAXV;
    }
    *reinterpret_cast<float4*>(&tile[r * LDS_STRIDE + 4 + c4 * 4]) = v;
  }

  // ---- structuring element: every thread computes all 49 weights (uniform),
  //      then pins them to SGPRs. Overlaps the staging loads' latency. ----
  const float k1v = k1p[0], k2v = k2p[0], k3v = k3p[0];
  float se[49];
#pragma unroll
  for (int i = 0; i < 49; ++i) {
    const float xg = (float)(i % 7 - 3);
    const float yg = (float)(i / 7 - 3);
    se[i] = k1v * (xg * xg) + 2.0f * k2v * (xg * yg) + k3v * (yg * yg);
  }
  float m = se[0];
#pragma unroll
  for (int i = 1; i < 49; ++i) m = fmaxf(m, se[i]);
  const float inv = 1.0f / m;
  float w[49];
#pragma unroll
  for (int i = 0; i < 49; ++i) w[i] = rfl((i == 24) ? -MAXV : (0.0f - se[i] * inv));

  __syncthreads();

  // ---- compute: lane-contiguous reads; thread owns 4 cols x 4 rows ----
  const int tx = tid & 63;                       // 64 lanes span the full row
  const int g = tid >> 6;                        // wave-row group 0..3
  const int r0 = g * R;                          // output row base within tile

  float acc[R][4];
#pragma unroll
  for (int t = 0; t < R; ++t)
#pragma unroll
    for (int c = 0; c < 4; ++c) acc[t][c] = -INFINITY;

#pragma unroll
  for (int iy = 0; iy < R + 6; ++iy) {           // input rows (LDS rows r0+iy)
    // 3 aligned b128s: LDS cols tx*4 .. tx*4+11  == gx tx*4-4 .. tx*4+7
    const float* rp = &tile[(r0 + iy) * LDS_STRIDE + tx * 4];
    float buf[12];
#pragma unroll
    for (int q = 0; q < 3; ++q) {
      const float4 v = *reinterpret_cast<const float4*>(rp + 4 * q);
      buf[4 * q + 0] = v.x;
      buf[4 * q + 1] = v.y;
      buf[4 * q + 2] = v.z;
      buf[4 * q + 3] = v.w;
    }
#pragma unroll
    for (int t = 0; t < R; ++t) {
      const int dyr = iy - t;                    // nb row index = dy+3
      if (dyr < 0 || dyr > 6) continue;          // dead after unroll
#pragma unroll
      for (int c = 0; c < 4; ++c) {
        // out col = tx*4+c uses gx tx*4+c-3..+3 -> buf[c+1..c+7]
        const float s0 = buf[c + 1] + w[dyr * 7 + 0];
        const float s1 = buf[c + 2] + w[dyr * 7 + 1];
        const float s2 = buf[c + 3] + w[dyr * 7 + 2];
        const float s3 = buf[c + 4] + w[dyr * 7 + 3];
        const float s4 = buf[c + 5] + w[dyr * 7 + 4];
        const float s5 = buf[c + 6] + w[dyr * 7 + 5];
        const float s6 = buf[c + 7] + w[dyr * 7 + 6];
        const float m0 = fmaxf(fmaxf(s0, s1), s2);   // v_max3
        const float m1 = fmaxf(fmaxf(s3, s4), s5);   // v_max3
        const float m01 = fmaxf(m0, m1);
        acc[t][c] = fmaxf(acc[t][c], fmaxf(m01, s6)); // v_max3(acc, m01, s6)
      }
    }
  }

  // ---- store: one float4 per output row, lane-contiguous across the wave ----
#pragma unroll
  for (int t = 0; t < R; ++t) {
    const int gy = ty0 + r0 + t;
    float4 v;
    v.x = acc[t][0];
    v.y = acc[t][1];
    v.z = acc[t][2];
    v.w = acc[t][3];
    *reinterpret_cast<float4*>(&op[gy * W + tx * 4]) = v;
  }
}

extern "C" void kernel_launch(void* const* d_in, const int* in_sizes, int n_in,
                              void* d_out, int out_size, void* d_ws, size_t ws_size,
                              hipStream_t stream) {
  const float* x = (const float*)d_in[0];
  const float* k1 = (const float*)d_in[1];
  const float* k2 = (const float*)d_in[2];
  const float* k3 = (const float*)d_in[3];
  float* outp = (float*)d_out;

  const int planes = 8 * 64;                     // 512
  const int blocks = planes * ROW_TILES;         // 8192
  morpho_kernel<<<dim3(blocks), dim3(256), 0, stream>>>(x, k1, k2, k3, outp);
}